// Round 13
// baseline (497.199 us; speedup 1.0000x reference)
//
#include <hip/hip_runtime.h>
#include <math.h>

#define C 320
#define NPTS 2048
#define SUPPTS 20480   // 2*5*2048 support points
#define QPTS 4096      // 2*2048 query points
#define KP 100         // prototypes per problem
#define NCLS 3
#define PSTRIDE 300    // transposed proto row stride (floats)
#define NB 400         // persistent grid: 400 blocks x 256 thr (cap 512 co-resident @ 2/CU)

// single-use device-scope grid barrier; bar[idx] must be zeroed before launch.
__device__ __forceinline__ void gridbar(int* bar, int idx) {
    __syncthreads();
    if (threadIdx.x == 0) {
        __threadfence();                       // release: flush this block's writes
        atomicAdd(&bar[idx], 1);
        long spins = 0;
        while (atomicAdd(&bar[idx], 0) < NB) { // device-scope poll (no stale L2)
            if (++spins > (1L << 27)) break;   // safety valve: fail fast, never hang
        }
        __threadfence();                       // acquire: invalidate stale lines
    }
    __syncthreads();
}

// Persistent mega-kernel: 8 former dispatches as phases split by manual grid barriers.
// Phase math verbatim from passed rounds (r11 / r6), only re-gridded.
__global__ __launch_bounds__(256, 2) void k_mega(const float* __restrict__ sup,
                                                 const float* __restrict__ qry,
                                                 const int* __restrict__ sy,
                                                 const int* __restrict__ qy,
                                                 float* __restrict__ out,
                                                 float* __restrict__ wsf) {
    // workspace layout
    float* qrn   = wsf;                      // 4096
    float* cnt   = qrn + QPTS;               // 4000
    float* pbufT = cnt + 4000;               // 96000
    float* phatT = pbufT + 96000;            // 96000
    float* loss  = phatT + 96000;            // 4 (loss[0], csum=loss[1])
    int*   bar   = (int*)(loss + 4);         // 8 ints (memset to 0 by host each launch)
    int*   dstb  = bar + 8;                  // 20480
    float* trans = (float*)(dstb + SUPPTS);
    float* pmaxv = trans;                    // [5][40960]
    int*   pmaxj = (int*)(pmaxv + 204800);
    float* part  = trans;                    // overlays pmax (phase B), 1,280,000 floats
    float* qmaxv = trans;                    // overlays again (phase C)
    float* cbuf  = qmaxv + 122880;
    int*   lbuf  = (int*)(cbuf + QPTS);

    __shared__ __align__(16) float smem[7200];   // 28.8 KB

    int bid = blockIdx.x, tid = threadIdx.x;

    // ---------------- P1: protoseed (300 wave-units) ----------------
    {
        int w = bid * 4 + (tid >> 6);
        int lane = tid & 63;
        if (w < 300) {
            int p = w;
            int prob = (p < 100) ? 2 : ((p < 200) ? 0 : 1);
            int rank = (p < 100) ? p : ((p < 200) ? p - 100 : p - 200);
            int M    = (prob == 2) ? SUPPTS : 10240;
            int base = (prob == 1) ? 10240 : 0;
            int found = 0, sp = 0;
            for (int chunk = 0; chunk < M; chunk += 64) {
                int yy = sy[base + chunk + lane];
                int m  = (prob == 2) ? (1 - yy) : yy;
                unsigned long long bal = __ballot(m != 0);
                int cb = __popcll(bal);
                if (found + cb > rank) {
                    int need = rank - found;
                    int prefix = __popcll(bal & ((1ull << lane) - 1ull));
                    unsigned long long match = __ballot(m && (prefix == need));
                    int pos = __ffsll(match) - 1;
                    sp = base + chunk + pos;
                    break;
                }
                found += cb;
            }
            const float* fb = sup + ((size_t)(sp >> 11) * C) * NPTS + (sp & 2047);
            float v[5]; float s = 0.f;
            #pragma unroll
            for (int i = 0; i < 5; i++) {
                v[i] = fb[(size_t)(lane + i * 64) * NPTS];
                s += v[i] * v[i];
            }
            #pragma unroll
            for (int off = 32; off > 0; off >>= 1) s += __shfl_down(s, off);
            s = __shfl(s, 0);
            float r = 1.0f / (sqrtf(s) + 1e-8f);
            #pragma unroll
            for (int i = 0; i < 5; i++)
                pbufT[(size_t)(lane + i * 64) * PSTRIDE + p] = v[i] * r;
        }
    }
    gridbar(bar, 0);

    // ---------------- P2: assign (400 units: 512 pts x 20-proto tile) ----------------
    {
        float* shp = smem;   // C*20 floats
        int b2 = bid % 80, jt = bid / 80;
        int prob, pt, gbase, aoff;
        if (b2 < 20)      { prob = 0; pt = b2 * 512;        gbase = 0;     aoff = 0; }
        else if (b2 < 40) { prob = 1; pt = (b2 - 20) * 512; gbase = 10240; aoff = 10240; }
        else              { prob = 2; pt = (b2 - 40) * 512; gbase = 0;     aoff = 20480; }
        int j0 = jt * 20;
        int col0 = (prob == 2) ? 0 : (100 + prob * 100);
        for (int i = tid; i < C * 20; i += 256) {
            int j = i % 20, c = i / 20;
            shp[i] = pbufT[(size_t)c * PSTRIDE + col0 + j0 + j];
        }
        __syncthreads();
        int g = gbase + pt + tid * 2;
        const float* fb = sup + ((size_t)(g >> 11) * C) * NPTS + (g & 2047);
        float acc0[20], acc1[20];
        #pragma unroll
        for (int j = 0; j < 20; j++) { acc0[j] = 0.f; acc1[j] = 0.f; }
        float2 pf[8];
        #pragma unroll
        for (int k = 0; k < 8; k++) pf[k] = *(const float2*)(fb + (size_t)k * NPTS);
        for (int cc = 0; cc < C; cc += 8) {
            float2 cur[8];
            #pragma unroll
            for (int k = 0; k < 8; k++) cur[k] = pf[k];
            if (cc + 8 < C) {
                #pragma unroll
                for (int k = 0; k < 8; k++) pf[k] = *(const float2*)(fb + (size_t)(cc + 8 + k) * NPTS);
            }
            #pragma unroll
            for (int k = 0; k < 8; k++) {
                const float4* r = (const float4*)&shp[(cc + k) * 20];
                float4 a = r[0], d1 = r[1], d2 = r[2], d3 = r[3], d4 = r[4];
                float px = cur[k].x, py = cur[k].y;
                acc0[0]+=px*a.x;  acc1[0]+=py*a.x;  acc0[1]+=px*a.y;  acc1[1]+=py*a.y;
                acc0[2]+=px*a.z;  acc1[2]+=py*a.z;  acc0[3]+=px*a.w;  acc1[3]+=py*a.w;
                acc0[4]+=px*d1.x; acc1[4]+=py*d1.x; acc0[5]+=px*d1.y; acc1[5]+=py*d1.y;
                acc0[6]+=px*d1.z; acc1[6]+=py*d1.z; acc0[7]+=px*d1.w; acc1[7]+=py*d1.w;
                acc0[8]+=px*d2.x; acc1[8]+=py*d2.x; acc0[9]+=px*d2.y; acc1[9]+=py*d2.y;
                acc0[10]+=px*d2.z;acc1[10]+=py*d2.z;acc0[11]+=px*d2.w;acc1[11]+=py*d2.w;
                acc0[12]+=px*d3.x;acc1[12]+=py*d3.x;acc0[13]+=px*d3.y;acc1[13]+=py*d3.y;
                acc0[14]+=px*d3.z;acc1[14]+=py*d3.z;acc0[15]+=px*d3.w;acc1[15]+=py*d3.w;
                acc0[16]+=px*d4.x;acc1[16]+=py*d4.x;acc0[17]+=px*d4.y;acc1[17]+=py*d4.y;
                acc0[18]+=px*d4.z;acc1[18]+=py*d4.z;acc0[19]+=px*d4.w;acc1[19]+=py*d4.w;
            }
        }
        float bv0 = acc0[0]; int bj0 = 0;
        float bv1 = acc1[0]; int bj1 = 0;
        #pragma unroll
        for (int j = 1; j < 20; j++) {
            if (acc0[j] > bv0) { bv0 = acc0[j]; bj0 = j; }
            if (acc1[j] > bv1) { bv1 = acc1[j]; bj1 = j; }
        }
        size_t a0 = (size_t)jt * 40960 + (aoff + pt + tid * 2);
        pmaxv[a0]     = bv0; pmaxj[a0]     = j0 + bj0;
        pmaxv[a0 + 1] = bv1; pmaxj[a0 + 1] = j0 + bj1;
    }
    gridbar(bar, 1);

    // ---------------- P3: combine -> dst; init loss/csum (80 blocks) ----------------
    if (bid < 80) {
        int g = bid * 256 + tid;
        if (g == 0) loss[0] = 0.f;
        if (g == 1) loss[1] = 0.f;
        float bvf = pmaxv[g]; int bjf = pmaxj[g];
        #pragma unroll
        for (int t = 1; t < 5; t++) {
            float v = pmaxv[(size_t)t * 40960 + g];
            if (v > bvf) { bvf = v; bjf = pmaxj[(size_t)t * 40960 + g]; }
        }
        float bvb = pmaxv[SUPPTS + g]; int bjb = pmaxj[SUPPTS + g];
        #pragma unroll
        for (int t = 1; t < 5; t++) {
            float v = pmaxv[(size_t)t * 40960 + SUPPTS + g];
            if (v > bvb) { bvb = v; bjb = pmaxj[(size_t)t * 40960 + SUPPTS + g]; }
        }
        int way = (g >= 10240) ? 1 : 0;
        dstb[g] = sy[g] ? (100 + way * 100 + bjf) : bjb;
    }
    gridbar(bar, 2);

    // ---------------- P4: accum, 800 units, 2 per block (4 parity copies) ----------------
    {
        float* bins = smem;          // 6400 floats
        float* scnt = smem + 6400;   // 800 floats
        int copy = tid & 3;
        for (int v = bid; v < 800; v += NB) {
            int bx = v % 20, ct = v / 20;
            int ws = bx >> 1, half = bx & 1;
            int w = (ws >= 5) ? 1 : 0;
            int nbase = half * 1024;
            for (int i = tid; i < 8 * 800; i += 256) bins[i] = 0.f;
            if (ct == 0) { for (int i = tid; i < 800; i += 256) scnt[i] = 0.f; }
            int dreg[4];
            #pragma unroll
            for (int sub = 0; sub < 4; sub++) {
                int d = dstb[ws * 2048 + nbase + sub * 256 + tid];
                dreg[sub] = (d < 100) ? d : (d - w * 100);
            }
            __syncthreads();
            if (ct == 0) {
                #pragma unroll
                for (int sub = 0; sub < 4; sub++) atomicAdd(&scnt[copy * 200 + dreg[sub]], 1.0f);
            }
            const float* base = sup + ((size_t)ws * C + ct * 8) * NPTS + nbase;
            for (int cl = 0; cl < 8; cl++) {
                const float* row = base + (size_t)cl * NPTS;
                #pragma unroll
                for (int sub = 0; sub < 4; sub++)
                    atomicAdd(&bins[cl * 800 + copy * 200 + dreg[sub]], row[sub * 256 + tid]);
            }
            __syncthreads();
            float* pout = part + (size_t)(bx * 40 + ct) * 1600;
            for (int i = tid; i < 8 * 200; i += 256) {
                int bin = i >> 3, cl = i & 7;
                pout[i] = bins[cl * 800 + bin] + bins[cl * 800 + 200 + bin]
                        + bins[cl * 800 + 400 + bin] + bins[cl * 800 + 600 + bin];
            }
            if (ct == 0 && tid < 200)
                cnt[bx * 200 + tid] = scnt[tid] + scnt[200 + tid] + scnt[400 + tid] + scnt[600 + tid];
            __syncthreads();   // LDS reuse across loop iterations
        }
    }
    gridbar(bar, 3);

    // ---------------- P5: reduce + mean + l2norm -> phatT (300 wave-units) ----------------
    {
        int w = bid * 4 + (tid >> 6);
        int lane = tid & 63;
        if (w < 300) {
            int d = w;
            int local, s0, ns;
            if (d < 100)      { local = d;       s0 = 0;  ns = 20; }
            else if (d < 200) { local = d;       s0 = 0;  ns = 10; }
            else              { local = d - 100; s0 = 10; ns = 10; }
            float dn = 0.f;
            for (int k = 0; k < ns; k++) dn += cnt[(s0 + k) * 200 + local];
            float inv = 1.0f / (dn + 1e-8f);
            float vals[5]; float sq = 0.f;
            #pragma unroll
            for (int i = 0; i < 5; i++) {
                int c = lane + i * 64;
                int ct = c >> 3, cl = c & 7;
                float s = 0.f;
                for (int k = 0; k < ns; k++)
                    s += part[(size_t)((s0 + k) * 40 + ct) * 1600 + local * 8 + cl];
                float v = s * inv;
                vals[i] = v; sq += v * v;
            }
            #pragma unroll
            for (int off = 32; off > 0; off >>= 1) sq += __shfl_down(sq, off);
            sq = __shfl(sq, 0);
            float rn = 1.0f / (sqrtf(sq) + 1e-8f);
            #pragma unroll
            for (int i = 0; i < 5; i++)
                phatT[(size_t)(lane + i * 64) * PSTRIDE + d] = vals[i] * rn;
        }
    }
    gridbar(bar, 4);

    // ---------------- P6: qpartial, 480 wave-units (pb,jt), jt block-uniform ----------------
    if (bid < 120) {
        float* shp = smem;   // C*16 floats
        int jt = bid % 30;
        int pb = (bid / 30) * 4 + (tid >> 6);
        int lane = tid & 63;
        int j0 = jt * 10;
        for (int i = tid; i < C * 10; i += 256) {
            int j = i % 10, c = i / 10;
            shp[c * 16 + j] = phatT[(size_t)c * PSTRIDE + j0 + j];
        }
        __syncthreads();
        int m = pb * 256 + lane * 4;
        const float* fb = qry + ((size_t)(m >> 11) * C) * NPTS + (m & 2047);
        float acc[4][10];
        #pragma unroll
        for (int p = 0; p < 4; p++)
            #pragma unroll
            for (int j = 0; j < 10; j++) acc[p][j] = 0.f;
        float qn[4] = {0.f, 0.f, 0.f, 0.f};
        float4 pf[8];
        #pragma unroll
        for (int k = 0; k < 8; k++) pf[k] = *(const float4*)(fb + (size_t)k * NPTS);
        for (int cc = 0; cc < C; cc += 8) {
            float4 cur[8];
            #pragma unroll
            for (int k = 0; k < 8; k++) cur[k] = pf[k];
            if (cc + 8 < C) {
                #pragma unroll
                for (int k = 0; k < 8; k++) pf[k] = *(const float4*)(fb + (size_t)(cc + 8 + k) * NPTS);
            }
            #pragma unroll
            for (int k = 0; k < 8; k++) {
                const float* row = &shp[(cc + k) * 16];
                float4 p0 = ((const float4*)row)[0];
                float4 p1 = ((const float4*)row)[1];
                float2 p2 = ((const float2*)row)[4];
                float pr[10] = {p0.x,p0.y,p0.z,p0.w,p1.x,p1.y,p1.z,p1.w,p2.x,p2.y};
                float4 cv = cur[k];
                if (jt == 0) {
                    qn[0] += cv.x*cv.x; qn[1] += cv.y*cv.y; qn[2] += cv.z*cv.z; qn[3] += cv.w*cv.w;
                }
                #pragma unroll
                for (int j = 0; j < 10; j++) {
                    acc[0][j] += cv.x * pr[j];
                    acc[1][j] += cv.y * pr[j];
                    acc[2][j] += cv.z * pr[j];
                    acc[3][j] += cv.w * pr[j];
                }
            }
        }
        #pragma unroll
        for (int p = 0; p < 4; p++) {
            float bv = acc[p][0];
            #pragma unroll
            for (int j = 1; j < 10; j++) bv = fmaxf(bv, acc[p][j]);
            qmaxv[(size_t)(m + p) * 30 + jt] = bv;
        }
        if (jt == 0) {
            #pragma unroll
            for (int p = 0; p < 4; p++) qrn[m + p] = 1.0f / (sqrtf(qn[p]) + 1e-8f);
        }
    }
    gridbar(bar, 5);

    // ---------------- P7: pred + CE loss + conf staging (16 blocks) ----------------
    if (bid < 16) {
        float* redL = smem;
        float* redC = smem + 256;
        int m = bid * 256 + tid;
        float rn = qrn[m];
        float pred[NCLS];
        #pragma unroll
        for (int cls = 0; cls < NCLS; cls++) {
            float g = qmaxv[(size_t)m * 30 + cls * 10];
            #pragma unroll
            for (int t = 1; t < 10; t++) g = fmaxf(g, qmaxv[(size_t)m * 30 + cls * 10 + t]);
            pred[cls] = rn * g;
        }
        int q = m >> 11, n = m & 2047;
        #pragma unroll
        for (int cls = 0; cls < NCLS; cls++)
            out[1 + ((size_t)(q * NCLS + cls)) * NPTS + n] = pred[cls];
        float mx = fmaxf(pred[0], fmaxf(pred[1], pred[2]));
        float lse = mx + logf(expf(pred[0] - mx) + expf(pred[1] - mx) + expf(pred[2] - mx));
        int lab = 0; float cf = pred[0];
        if (pred[1] > cf) { cf = pred[1]; lab = 1; }
        if (pred[2] > cf) { cf = pred[2]; lab = 2; }
        cbuf[m] = cf; lbuf[m] = lab;
        redL[tid] = lse - pred[qy[m]];
        redC[tid] = cf;
        __syncthreads();
        for (int off = 128; off > 0; off >>= 1) {
            if (tid < off) { redL[tid] += redL[tid + off]; redC[tid] += redC[tid + off]; }
            __syncthreads();
        }
        if (tid == 0) {
            atomicAdd(&loss[0], redL[0]);
            atomicAdd(&loss[1], redC[0]);
        }
    }
    gridbar(bar, 6);

    // ---------------- P8: final labels + loss (16 blocks) ----------------
    if (bid < 16) {
        int m = bid * 256 + tid;
        float mean = loss[1] / (float)QPTS;
        float cf = cbuf[m];
        out[1 + 2 * NCLS * NPTS + m] = (cf > mean) ? (float)lbuf[m] : -1.0f;
        if (m == 0) out[0] = 2.0f * loss[0] / (float)QPTS;
    }
}

extern "C" void kernel_launch(void* const* d_in, const int* in_sizes, int n_in,
                              void* d_out, int out_size, void* d_ws, size_t ws_size,
                              hipStream_t stream) {
    const float* sup = (const float*)d_in[0];   // [2,5,320,2048]
    const float* qry = (const float*)d_in[1];   // [2,320,2048]
    const int*   sy  = (const int*)d_in[2];     // [2,5,2048]
    const int*   qy  = (const int*)d_in[3];     // [2,2048]
    float* out = (float*)d_out;
    float* wsf = (float*)d_ws;

    // barrier slots live right after the 4-float loss area
    int* bar = (int*)(wsf + QPTS + 4000 + 96000 + 96000 + 4);
    hipMemsetAsync(bar, 0, 8 * sizeof(int), stream);

    k_mega<<<NB, 256, 0, stream>>>(sup, qry, sy, qy, out, wsf);
}